// Round 7
// baseline (100.012 us; speedup 1.0000x reference)
//
#include <hip/hip_runtime.h>
#include <hip/hip_fp16.h>
#include <math.h>

// ---- nearest-neighbor LUT: 8192 floats over d in [-0.2, 1.27456), h=1.8e-4 ----
// BYTE index = (d - LO) * INVH4, clamped to [0, 32764]. f is EXACTLY 0 for
// d >= 1.27 (both softplus args clip), so taps with v-theta beyond band are
// skippable; lut[8191] itself evaluates to exactly 0 too.
#define NLUT    8192
#define LUT_LO  (-0.2)
#define LUT_H   (1.8e-4)
#define INVH4   22222.222222222f   // 4/LUT_H (byte-scaled index)
#define BLIM    32764.0f           // (NLUT-1)*4
#define BAND_LO (-0.35f)
#define BAND_HI (1.28f)
// conv1 dead-pixel threshold: v > VDEAD -> d > 1.27 for ALL theta1<=4.8 -> f==0
#define VDEAD   6.08f
// static conservative theta2 window (theta2 ~ U[2.8,4.8] by problem spec)
#define WLO     (2.8f + BAND_LO)   // 2.45
#define WHI     (4.8f + BAND_HI)   // 6.08

// ---- ws layout (bytes) ----
#define WS_LUT    0          // float[8192]            32768
#define WS_TH2T   32768      // float[36864]           147456 -> 180224
#define WS_TNEG   180224     // float[36864]           147456 -> 327680
#define WS_C2H    327680     // __half[262144]         524288 -> 851968
#define WS_AM     851968     // u64[4096]              32768  -> 884736 (alive masks; reused by k3 as conv2 masks)
#define WS_S8     884736     // float[8*128]           4096   -> 888832 (BN1 partial replicas)
#define WS_SUMS2  888832     // float[128]             512    -> 889344
#define WS_TOTAL  889344

__device__ __forceinline__ double f_exact(double d) {
    const double nvt = 1.5 * 0.026;
    double a1 = d / nvt;         a1 = fmin(fmax(a1, -30.0), 30.0);
    double a2 = (d - 0.1) / nvt; a2 = fmin(fmax(a2, -30.0), 30.0);
    double s1 = log1p(exp(a1));
    double s2 = log1p(exp(a2));
    return 0.0005625 * (s1 * s1 - s2 * s2);
}

// K0: blk<32 LUT | <176 th2t transpose | <320 tneg1 build | <336 alive masks | 336 zero sums
__global__ __launch_bounds__(256) void k0_prep(
    const float* __restrict__ x,
    const float* __restrict__ theta1, const float* __restrict__ theta2,
    const float* __restrict__ psc, const float* __restrict__ psh,
    float* __restrict__ lutg, float* __restrict__ th2t, float* __restrict__ tneg,
    unsigned long long* __restrict__ am, float* __restrict__ zerow)
{
    int blk = blockIdx.x, tid = threadIdx.x;
    if (blk < 32) {
        int i = blk * 256 + tid;                       // 0..8191
        double d = LUT_LO + ((double)i + 0.5) * LUT_H; // cell center
        lutg[i] = (float)f_exact(d);
    } else if (blk < 176) {
        int i = (blk - 32) * 256 + tid;                // 0..36863
        int p = i & 63, k = i >> 6;
        th2t[k * 64 + p] = theta2[p * 576 + k];
    } else if (blk < 320) {
        int i = (blk - 176) * 256 + tid;               // 0..36863 = p*576 + k
        int p = i / 576;
        int k = i - p * 576;
        int c = k / 9;
        int t = k - c * 9;
        float val = (psh[0] - (float)LUT_LO - theta1[i]) * INVH4;
        tneg[((t << 6) + c) * 64 + p] = val;           // [t][c][p]
    } else if (blk < 336) {
        // alive masks: wave covers 2 pixel rows; lane=(r,px); loop c building bits
        int wv = __builtin_amdgcn_readfirstlane(tid >> 6);
        int lane = tid & 63;
        int gw = (blk - 320) * 4 + wv;                 // 0..63
        int r = lane >> 5, px = lane & 31;
        int rowg = gw * 2 + r;                         // 0..127
        int b = rowg >> 5, y = rowg & 31;
        float T = (VDEAD - psh[0]) / psc[0];
        const float* xb = x + b * 65536 + y * 32 + px;
        unsigned long long m = 0ull;
        #pragma unroll 8
        for (int c = 0; c < 64; ++c)
            m |= (unsigned long long)(xb[c * 1024] < T) << c;
        am[b * 1024 + y * 32 + px] = m;
    } else {
        // zero s8 + sums2 (1152 words)
        float* z = zerow;
        for (int i = tid; i < 1152; i += 256) z[i] = 0.f;
    }
}

// K1: sparse dense-out conv1. grid 1024 x 256 (wave per output pixel, lane=plane).
// Wave-uniform mask walk over alive (c,t); uniform x via s_load; theta via
// coalesced VMEM; LUT gather in LDS. Pixel-major coalesced output (= d_out).
// BN1 partial sums via block LDS reduce + 8-replica atomics.
__global__ __launch_bounds__(256, 4) void k1_conv1(
    const float* __restrict__ x, const float* __restrict__ tneg,
    const unsigned long long* __restrict__ am,
    const float* __restrict__ psc, const float* __restrict__ ls1,
    const float* __restrict__ lutg,
    float* __restrict__ rawpm, float* __restrict__ s8)
{
    __shared__ float lut[NLUT];
    __shared__ float psum[4][64], psq[4][64];
    {
        const float4* s = (const float4*)lutg;
        float4* d = (float4*)lut;
        for (int i = threadIdx.x; i < NLUT / 4; i += 256) d[i] = s[i];
    }
    __syncthreads();

    int wv   = __builtin_amdgcn_readfirstlane((int)threadIdx.x >> 6);
    int lane = threadIdx.x & 63;
    int P = blockIdx.x * 4 + wv;                   // 0..4095
    int b = P >> 10, pix = P & 1023;
    int y = pix >> 5, xc = pix & 31;

    float SC4 = psc[0] * INVH4;                    // loop-invariant (lives in VGPR)
    const float* xb = x + b * 65536;
    float acc = 0.f;

    #pragma unroll
    for (int t = 0; t < 9; ++t) {
        int ny = y + t / 3 - 1, nx = xc + t % 3 - 1;
        if ((unsigned)ny >= 32u || (unsigned)nx >= 32u) continue;   // uniform
        int tp = ny * 32 + nx;
        unsigned long long mk = am[b * 1024 + tp];                  // uniform -> s_load
        const float* tb = tneg + (t << 12);        // [t][c][p]
        while (mk) {
            int c = __ffsll((long long)mk) - 1;
            mk &= mk - 1;
            float xv = xb[c * 1024 + tp];          // uniform -> s_load
            float th = tb[(c << 6) + lane];        // coalesced 256B VMEM
            float q = fmaf(xv, SC4, th);           // (v - theta - LO)*INVH4
            q = fminf(fmaxf(q, 0.f), BLIM);        // v_med3
            int qb = (int)q & ~3;
            acc += *(const float*)((const char*)lut + qb);
        }
    }

    float r0 = ls1[0] * acc;
    rawpm[P * 64 + lane] = r0;                     // pixel-major, coalesced

    psum[wv][lane] = r0;
    psq[wv][lane]  = r0 * r0;
    __syncthreads();
    if (wv == 0) {
        float s  = psum[0][lane] + psum[1][lane] + psum[2][lane] + psum[3][lane];
        float qq = psq[0][lane]  + psq[1][lane]  + psq[2][lane]  + psq[3][lane];
        int r8 = (blockIdx.x & 7) * 128;
        atomicAdd(&s8[r8 + lane], s);
        atomicAdd(&s8[r8 + 64 + lane], qq);
    }
}

// K3: BN1 apply (stats from 8 replicas) + conv2 masks via ballot. wave/pixel, lane=c.
__global__ __launch_bounds__(256) void k3_bn1mask(float* __restrict__ v2,
    const float* __restrict__ s8, const float* __restrict__ g1,
    const float* __restrict__ b1, unsigned long long* __restrict__ masks)
{
    int wv   = __builtin_amdgcn_readfirstlane((int)threadIdx.x >> 6);
    int lane = threadIdx.x & 63;
    int P = blockIdx.x * 4 + wv;                   // 0..4095
    float s = 0.f, q = 0.f;
    #pragma unroll
    for (int r = 0; r < 8; ++r) {
        s += s8[r * 128 + lane];
        q += s8[r * 128 + 64 + lane];
    }
    float m   = s * (1.f / 4096.f);
    float var = q * (1.f / 4096.f) - m * m;
    var = fmaxf(var, 0.f);
    float rstd = rsqrtf(var + 1e-5f);
    float sc = rstd * g1[lane];
    float sh = b1[lane] - m * sc;
    float v = v2[P * 64 + lane];
    v = fmaf(v, sc, sh);
    v2[P * 64 + lane] = v;
    unsigned long long blt = __ballot(v > WLO && v < WHI);
    if (lane == 0) masks[P] = blt;
}

// K4: sparse conv2 (pixel-major input). wave/pixel, lane = output plane. Exact f32.
__global__ __launch_bounds__(256) void k4_conv2(const float* __restrict__ v2,
    const float* __restrict__ th2t, const unsigned long long* __restrict__ masks,
    const float* __restrict__ ls2, __half* __restrict__ c2h, float* __restrict__ sums2)
{
    int wv = __builtin_amdgcn_readfirstlane((int)threadIdx.x >> 6);
    int lane = threadIdx.x & 63;
    int P = blockIdx.x * 4 + wv;                   // 0..4095
    int b = P >> 10, rem = P & 1023;
    int y = rem >> 5, xq = rem & 31;
    float l2 = ls2[0];
    const float inv_nvt = (float)(1.0 / (1.5 * 0.026));
    float acc = 0.f;

    #pragma unroll
    for (int j = 0; j < 9; ++j) {
        int ny = y + j / 3 - 1, nx = xq + j % 3 - 1;
        if ((unsigned)ny < 32u && (unsigned)nx < 32u) {
            int tp = ny * 32 + nx;
            unsigned long long mk = masks[b * 1024 + tp];
            while (mk) {
                int c = __ffsll((long long)mk) - 1;
                mk &= mk - 1;
                float v  = v2[(b * 1024 + tp) * 64 + c];            // uniform
                float th = th2t[(c * 9 + j) * 64 + lane];           // coalesced
                float d = v - th;
                if (d > BAND_LO && d < BAND_HI) {
                    float a1 = fminf(fmaxf(d * inv_nvt, -30.f), 30.f);
                    float a2 = fminf(fmaxf((d - 0.1f) * inv_nvt, -30.f), 30.f);
                    float s1 = __logf(1.f + __expf(a1));
                    float s2 = __logf(1.f + __expf(a2));
                    acc += (s1 * s1 - s2 * s2);
                }
            }
        }
    }
    float r2 = 0.0005625f * l2 * acc;
    c2h[((b * 64 + lane) * 32 + y) * 32 + xq] = __float2half(r2);   // channel-major

    __shared__ float ss[256], sq[256];
    ss[threadIdx.x] = r2; sq[threadIdx.x] = r2 * r2;
    __syncthreads();
    if (threadIdx.x < 64) {
        float a  = ss[threadIdx.x] + ss[threadIdx.x + 64] + ss[threadIdx.x + 128] + ss[threadIdx.x + 192];
        float qq = sq[threadIdx.x] + sq[threadIdx.x + 64] + sq[threadIdx.x + 128] + sq[threadIdx.x + 192];
        atomicAdd(&sums2[threadIdx.x], a);
        atomicAdd(&sums2[64 + threadIdx.x], qq);
    }
}

// K6: BN2 apply + residual, c2h -> d_out. float4 on x/out, half2 on c2.
__global__ __launch_bounds__(256) void k6_final(float* __restrict__ out,
    const float* __restrict__ x, const __half* __restrict__ c2h,
    const float* __restrict__ sums2,
    const float* __restrict__ g2, const float* __restrict__ b2)
{
    int i4 = blockIdx.x * 256 + threadIdx.x;       // 0..65535
    int idx = i4 * 4;
    int p = (idx >> 10) & 63;
    float m   = sums2[p] * (1.f / 4096.f);
    float var = sums2[64 + p] * (1.f / 4096.f) - m * m;
    var = fmaxf(var, 0.f);
    float rstd = rsqrtf(var + 1e-5f);
    float sc = rstd * g2[p];
    float sh = b2[p] - m * sc;
    const __half2* ch = (const __half2*)c2h;
    __half2 h0 = ch[i4 * 2], h1 = ch[i4 * 2 + 1];
    float2 c01 = __half22float2(h0), c23 = __half22float2(h1);
    float4 xv = ((const float4*)x)[i4];
    float4 o;
    o.x = fmaf(c01.x, sc, sh) + xv.x;
    o.y = fmaf(c01.y, sc, sh) + xv.y;
    o.z = fmaf(c23.x, sc, sh) + xv.z;
    o.w = fmaf(c23.y, sc, sh) + xv.w;
    ((float4*)out)[i4] = o;
}

extern "C" void kernel_launch(void* const* d_in, const int* in_sizes, int n_in,
                              void* d_out, int out_size, void* d_ws, size_t ws_size,
                              hipStream_t stream)
{
    const float* x   = (const float*)d_in[0];
    const float* th1 = (const float*)d_in[1];
    const float* th2 = (const float*)d_in[2];
    const float* psc = (const float*)d_in[3];
    const float* psh = (const float*)d_in[4];
    const float* l1  = (const float*)d_in[5];
    const float* l2  = (const float*)d_in[6];
    const float* g1  = (const float*)d_in[7];
    const float* b1  = (const float*)d_in[8];
    const float* g2  = (const float*)d_in[9];
    const float* b2  = (const float*)d_in[10];
    float* out = (float*)d_out;
    char* ws = (char*)d_ws;
    if (ws_size < (size_t)WS_TOTAL) return;  // defensive: leave output poisoned

    float*  lutg = (float*)(ws + WS_LUT);
    float*  th2t = (float*)(ws + WS_TH2T);
    float*  tneg = (float*)(ws + WS_TNEG);
    __half* c2h  = (__half*)(ws + WS_C2H);
    unsigned long long* am = (unsigned long long*)(ws + WS_AM);
    float*  s8   = (float*)(ws + WS_S8);
    float*  sums2 = (float*)(ws + WS_SUMS2);

    float* rawpm = out;  // conv1 output (pixel-major) lives in d_out until k6

    k0_prep   <<<337,  256, 0, stream>>>(x, th1, th2, psc, psh,
                                         lutg, th2t, tneg, am, s8);
    k1_conv1  <<<1024, 256, 0, stream>>>(x, tneg, am, psc, l1, lutg, rawpm, s8);
    k3_bn1mask<<<1024, 256, 0, stream>>>(rawpm, s8, g1, b1, am);
    k4_conv2  <<<1024, 256, 0, stream>>>(rawpm, th2t, am, l2, c2h, sums2);
    k6_final  <<<256,  256, 0, stream>>>(out, x, c2h, sums2, g2, b2);
}